// Round 4
// baseline (2194.674 us; speedup 1.0000x reference)
//
#include <hip/hip_runtime.h>
#include <math.h>

typedef __attribute__((ext_vector_type(8))) short short8;
typedef __attribute__((ext_vector_type(8))) __bf16 bf16x8;
typedef __attribute__((ext_vector_type(4))) float f32x4;

static constexpr int H = 1024, LNUM = 4, SEQ = 2048, BATCH = 2;
static constexpr int TOK = BATCH * SEQ;       // 4096
static constexpr int NI = 4096, QKVD = H + 128; // 1152

__device__ __forceinline__ short f2bf(float f) {   // RNE fp32->bf16 bits
  union { float f; unsigned u; } c; c.f = f;
  return (short)((c.u + 0x7fffu + ((c.u >> 16) & 1u)) >> 16);
}

__device__ __forceinline__ void gl_lds16(const short* g, short* l) {
  __builtin_amdgcn_global_load_lds(
      (const __attribute__((address_space(1))) unsigned*)g,
      (__attribute__((address_space(3))) unsigned*)l, 16, 0, 0);
}

#define MFMA16(a, b, c) __builtin_amdgcn_mfma_f32_16x16x32_bf16(a, b, c, 0, 0, 0)

// ---------------------------------------------------------------- embedding
__global__ __launch_bounds__(256) void embed_kernel(
    const int* __restrict__ ids, const int* __restrict__ pos,
    const float* __restrict__ wte, const float* __restrict__ wpe,
    float* __restrict__ h) {
  int i = blockIdx.x * 256 + threadIdx.x;
  int tok = i >> 10, d = i & 1023;
  h[i] = wte[(size_t)ids[tok] * H + d] + wpe[(size_t)pos[tok] * H + d];
}

// ---------------------------------------------------------------- fp32 -> bf16 cast (weights)
__global__ __launch_bounds__(256) void cast_kernel(
    const float* __restrict__ src, short* __restrict__ dst) {
  int i = blockIdx.x * 256 + threadIdx.x;
  float4 v = ((const float4*)src)[i];
  union { short s[4]; uint2 u; } p;
  p.s[0] = f2bf(v.x); p.s[1] = f2bf(v.y); p.s[2] = f2bf(v.z); p.s[3] = f2bf(v.w);
  ((uint2*)dst)[i] = p.u;
}

// ---------------------------------------------------------------- layernorm (fp32 in; bf16 or fp32 out)
template <bool BF16_OUT>
__global__ __launch_bounds__(256) void ln_kernel(
    const float* __restrict__ X, const float* __restrict__ w,
    const float* __restrict__ b, void* __restrict__ out) {
  int row = blockIdx.x;
  const float* x = X + (size_t)row * H;
  int tid = threadIdx.x, lane = tid & 63, wid = tid >> 6;
  float v[4];
#pragma unroll
  for (int i = 0; i < 4; i++) v[i] = x[tid + i * 256];
  float s = v[0] + v[1] + v[2] + v[3];
#pragma unroll
  for (int off = 32; off > 0; off >>= 1) s += __shfl_xor(s, off);
  __shared__ float red[8];
  if (lane == 0) red[wid] = s;
  __syncthreads();
  float mu = (red[0] + red[1] + red[2] + red[3]) * (1.0f / H);
  float q = 0.f;
#pragma unroll
  for (int i = 0; i < 4; i++) { float d = v[i] - mu; q += d * d; }
#pragma unroll
  for (int off = 32; off > 0; off >>= 1) q += __shfl_xor(q, off);
  if (lane == 0) red[4 + wid] = q;
  __syncthreads();
  float var = (red[4] + red[5] + red[6] + red[7]) * (1.0f / H);
  float inv = rsqrtf(var + 1e-5f);
#pragma unroll
  for (int i = 0; i < 4; i++) {
    int col = tid + i * 256;
    float r = (v[i] - mu) * inv * w[col] + b[col];
    if (BF16_OUT) ((short*)out)[(size_t)row * H + col] = f2bf(r);
    else          ((float*)out)[(size_t)row * H + col] = r;
  }
}

// ---------------------------------------------------------------- V transpose: qkv V cols -> vt[b][64][SEQ]
__global__ __launch_bounds__(256) void vtrans_kernel(
    const short* __restrict__ qkv, short* __restrict__ vt) {
  __shared__ short Vs[64 * 68];
  int t0 = blockIdx.x * 64, b = blockIdx.y;
  int tid = threadIdx.x;
  int t = tid >> 2;
#pragma unroll
  for (int it = 0; it < 2; ++it) {
    int seg = (tid & 3) + it * 4;
    *(short8*)&Vs[t * 68 + seg * 8] =
        *(const short8*)(qkv + ((size_t)(b * SEQ) + t0 + t) * QKVD + 1088 + seg * 8);
  }
  __syncthreads();
  int tg = tid & 7;
#pragma unroll
  for (int it = 0; it < 2; ++it) {
    int d = (tid >> 3) + it * 32;
    short8 v;
#pragma unroll
    for (int e = 0; e < 8; ++e) v[e] = Vs[(tg * 8 + e) * 68 + d];
    *(short8*)(vt + ((size_t)(b * 64) + d) * SEQ + t0 + tg * 8) = v;
  }
}

// ---------------------------------------------------------------- MFMA GEMM: C = A(M,K)bf16 * W(N,K)bf16^T + bias(f32)
// MODE 0: C(bf16) = r   MODE 1: C(f32) += r   MODE 2: C(bf16) = gelu(r)
// BM=128, BN in {128,64}. 256 thr = 4 waves; BN=128: 2x2 waves of 64x64;
// BN=64: 4x1 waves of 32x64 (more blocks for narrow-N GEMMs -> 2+ blocks/CU).
template <int BN, int MODE>
__global__ __launch_bounds__(256) void gemm_mfma(
    const short* __restrict__ A, const short* __restrict__ W,
    const float* __restrict__ bias, void* __restrict__ Cv,
    int M, int N, int K) {
  __shared__ short As[128 * 32];
  __shared__ short Bs[BN * 32];
  constexpr int MI = (BN == 128) ? 4 : 2;
  int tid = threadIdx.x, wave = tid >> 6, lane = tid & 63;
  int li = lane & 15, lg = lane >> 4;
  int row0 = blockIdx.y * 128, col0 = blockIdx.x * BN;
  int wm = (BN == 128) ? (wave & 1) * 64 : wave * 32;
  int wn = (BN == 128) ? (wave >> 1) * 64 : 0;
  f32x4 acc[MI][4] = {};
  const short* Ab = A + (size_t)(row0 + (tid >> 2)) * K + (tid & 3) * 8;
  const short* Wb = W + (size_t)(col0 + (tid >> 2)) * K + (tid & 3) * 8;
  for (int k0 = 0; k0 < K; k0 += 32) {
    __syncthreads();
    gl_lds16(Ab + k0,          As + tid * 8);
    gl_lds16(Ab + k0 + 64 * K, As + 2048 + tid * 8);
    gl_lds16(Wb + k0,          Bs + tid * 8);
    if (BN == 128) gl_lds16(Wb + k0 + 64 * K, Bs + 2048 + tid * 8);
    __syncthreads();
    bf16x8 af[MI], bfr[4];
#pragma unroll
    for (int i = 0; i < MI; ++i)
      af[i] = *(const bf16x8*)&As[(wm + i * 16 + li) * 32 + lg * 8];
#pragma unroll
    for (int j = 0; j < 4; ++j)
      bfr[j] = *(const bf16x8*)&Bs[(wn + j * 16 + li) * 32 + lg * 8];
#pragma unroll
    for (int i = 0; i < MI; ++i)
#pragma unroll
      for (int j = 0; j < 4; ++j) acc[i][j] = MFMA16(af[i], bfr[j], acc[i][j]);
  }
  float* Cf = (float*)Cv;
  short* Cs = (short*)Cv;
#pragma unroll
  for (int i = 0; i < MI; ++i) {
    int gr = row0 + wm + i * 16 + lg * 4;
#pragma unroll
    for (int j = 0; j < 4; ++j) {
      int gc = col0 + wn + j * 16 + li;
      float bv = bias[gc];
#pragma unroll
      for (int r = 0; r < 4; ++r) {
        float v = acc[i][j][r] + bv;
        size_t idx = (size_t)(gr + r) * N + gc;
        if (MODE == 1) {
          Cf[idx] += v;
        } else if (MODE == 2) {
          v = 0.5f * v * (1.0f + erff(v * 0.70710678118654752f));
          Cs[idx] = f2bf(v);
        } else {
          Cs[idx] = f2bf(v);
        }
      }
    }
  }
}

// ---------------------------------------------------------------- MFMA flash MQA attention (barrier-free)
// qkv bf16 [TOK][1152]; vt bf16 [b][64][SEQ]; out bf16 [TOK][1024].
// Block 256 = 4 waves; block = (qt rev, head, b); wave w owns q-rows w*16..+15.
// K/V frags read directly from global (L2-resident, 16x head reuse); only P
// round-trips LDS (per-wave private -> no __syncthreads anywhere).
__global__ __launch_bounds__(256) void mqa_attn(
    const short* __restrict__ qkv, const short* __restrict__ vt,
    short* __restrict__ out) {
  int qt = gridDim.x - 1 - blockIdx.x;   // heavy tiles dispatch first
  int head = blockIdx.y, b = blockIdx.z;
  int tid = threadIdx.x, wave = tid >> 6, lane = tid & 63;
  int li = lane & 15, lg = lane >> 4;

  __shared__ short Ps[4 * 16 * 72];      // per-wave P [m][t], pad 8

  const size_t qrow0 = (size_t)(b * SEQ + qt * 64);
  bf16x8 qf[2];
  {
    const short* qp = qkv + (qrow0 + wave * 16 + li) * QKVD + head * 64 + lg * 8;
    qf[0] = *(const bf16x8*)(qp);
    qf[1] = *(const bf16x8*)(qp + 32);
  }
  f32x4 oacc[4] = {};
  float m_i[4], l_i[4];
#pragma unroll
  for (int r = 0; r < 4; ++r) { m_i[r] = -1e30f; l_i[r] = 0.f; }
  short* pw = Ps + wave * 1152;

  for (int j = 0; j <= qt; ++j) {
    const short* kb = qkv + ((size_t)(b * SEQ + j * 64)) * QKVD + 1024;
    const short* vb = vt + (size_t)(b * 64) * SEQ + j * 64;
    // S = Q K^T : K B-frags straight from global (16B contiguous per lane)
    f32x4 s[4];
#pragma unroll
    for (int n = 0; n < 4; ++n) {
      const short* kr = kb + (size_t)(n * 16 + li) * QKVD + lg * 8;
      f32x4 a = {};
      a = MFMA16(qf[0], *(const bf16x8*)kr, a);
      a = MFMA16(qf[1], *(const bf16x8*)(kr + 32), a);
      s[n] = a;
    }
    bool diag = (j == qt);
#pragma unroll
    for (int n = 0; n < 4; ++n)
#pragma unroll
      for (int r = 0; r < 4; ++r) {
        float v = s[n][r] * 0.125f;
        if (diag && (n * 16 + li) > (wave * 16 + lg * 4 + r)) v = -1e30f;
        s[n][r] = v;
      }
    float alpha[4];
#pragma unroll
    for (int r = 0; r < 4; ++r) {
      float mx = fmaxf(fmaxf(s[0][r], s[1][r]), fmaxf(s[2][r], s[3][r]));
#pragma unroll
      for (int off = 1; off < 16; off <<= 1) mx = fmaxf(mx, __shfl_xor(mx, off));
      float mn = fmaxf(m_i[r], mx);
      alpha[r] = __expf(m_i[r] - mn);
      m_i[r] = mn;
      float ps = 0.f;
#pragma unroll
      for (int n = 0; n < 4; ++n) {
        float p = __expf(s[n][r] - mn);
        s[n][r] = p;
        ps += p;
      }
#pragma unroll
      for (int off = 1; off < 16; off <<= 1) ps += __shfl_xor(ps, off);
      l_i[r] = l_i[r] * alpha[r] + ps;
    }
#pragma unroll
    for (int dn = 0; dn < 4; ++dn)
#pragma unroll
      for (int r = 0; r < 4; ++r) oacc[dn][r] *= alpha[r];
#pragma unroll
    for (int n = 0; n < 4; ++n)
#pragma unroll
      for (int r = 0; r < 4; ++r) pw[(lg * 4 + r) * 72 + n * 16 + li] = f2bf(s[n][r]);
    // O += P V : P A-frag via LDS (per-wave), V B-frag straight from vt
#pragma unroll
    for (int ks = 0; ks < 2; ++ks) {
      bf16x8 pf = *(const bf16x8*)&pw[li * 72 + ks * 32 + lg * 8];
#pragma unroll
      for (int dn = 0; dn < 4; ++dn) {
        bf16x8 vf = *(const bf16x8*)(vb + (size_t)(dn * 16 + li) * SEQ + ks * 32 + lg * 8);
        oacc[dn] = MFMA16(pf, vf, oacc[dn]);
      }
    }
  }
#pragma unroll
  for (int r = 0; r < 4; ++r) {
    float inv = 1.0f / l_i[r];
    size_t row = (qrow0 + wave * 16 + lg * 4 + r) * H + head * 64;
#pragma unroll
    for (int dn = 0; dn < 4; ++dn) out[row + dn * 16 + li] = f2bf(oacc[dn][r] * inv);
  }
}

// ---------------------------------------------------------------- launch
extern "C" void kernel_launch(void* const* d_in, const int* in_sizes, int n_in,
                              void* d_out, int out_size, void* d_ws, size_t ws_size,
                              hipStream_t stream) {
  const int*   input_ids    = (const int*)d_in[0];
  const int*   position_ids = (const int*)d_in[1];
  const float* wte     = (const float*)d_in[2];
  const float* wpe     = (const float*)d_in[3];
  const float* ln1_w   = (const float*)d_in[4];
  const float* ln1_b   = (const float*)d_in[5];
  const float* cattn_w = (const float*)d_in[6];
  const float* cattn_b = (const float*)d_in[7];
  const float* cproj_w = (const float*)d_in[8];
  const float* cproj_b = (const float*)d_in[9];
  const float* ln2_w   = (const float*)d_in[10];
  const float* ln2_b   = (const float*)d_in[11];
  const float* fc_w    = (const float*)d_in[12];
  const float* fc_b    = (const float*)d_in[13];
  const float* mproj_w = (const float*)d_in[14];
  const float* mproj_b = (const float*)d_in[15];
  const float* lnf_w   = (const float*)d_in[16];
  const float* lnf_b   = (const float*)d_in[17];

  float* h     = (float*)d_ws;                    // TOK*H f32
  short* xbf   = (short*)(h + (size_t)TOK * H);   // TOK*H bf16
  short* qkvbf = xbf + (size_t)TOK * H;           // TOK*QKVD bf16
  short* fcbf  = qkvbf + (size_t)TOK * QKVD;      // TOK*NI bf16
  short* wqkv  = fcbf + (size_t)TOK * NI;         // per-layer bf16 weights
  short* wcp   = wqkv + (size_t)QKVD * H;
  short* wfc   = wcp + (size_t)H * H;
  short* wmp   = wfc + (size_t)NI * H;
  short* vt    = wmp + (size_t)H * NI;            // BATCH*64*SEQ bf16

  embed_kernel<<<TOK * H / 256, 256, 0, stream>>>(input_ids, position_ids, wte, wpe, h);

  for (int l = 0; l < LNUM; l++) {
    cast_kernel<<<QKVD * H / 1024, 256, 0, stream>>>(cattn_w + (size_t)l * QKVD * H, wqkv);
    cast_kernel<<<H * H / 1024, 256, 0, stream>>>(cproj_w + (size_t)l * H * H, wcp);
    cast_kernel<<<NI * H / 1024, 256, 0, stream>>>(fc_w + (size_t)l * NI * H, wfc);
    cast_kernel<<<H * NI / 1024, 256, 0, stream>>>(mproj_w + (size_t)l * H * NI, wmp);

    ln_kernel<true><<<TOK, 256, 0, stream>>>(h, ln1_w + l * H, ln1_b + l * H, xbf);
    gemm_mfma<64, 0><<<dim3(QKVD / 64, TOK / 128), 256, 0, stream>>>(
        xbf, wqkv, cattn_b + (size_t)l * QKVD, qkvbf, TOK, QKVD, H);
    vtrans_kernel<<<dim3(SEQ / 64, BATCH), 256, 0, stream>>>(qkvbf, vt);
    mqa_attn<<<dim3(32, 16, BATCH), 256, 0, stream>>>(qkvbf, vt, xbf);
    gemm_mfma<64, 1><<<dim3(H / 64, TOK / 128), 256, 0, stream>>>(
        xbf, wcp, cproj_b + (size_t)l * H, h, TOK, H, H);
    ln_kernel<true><<<TOK, 256, 0, stream>>>(h, ln2_w + l * H, ln2_b + l * H, xbf);
    gemm_mfma<128, 2><<<dim3(NI / 128, TOK / 128), 256, 0, stream>>>(
        xbf, wfc, fc_b + (size_t)l * NI, fcbf, TOK, NI, H);
    gemm_mfma<64, 1><<<dim3(H / 64, TOK / 128), 256, 0, stream>>>(
        fcbf, wmp, mproj_b + (size_t)l * H, h, TOK, H, NI);
  }
  ln_kernel<false><<<TOK, 256, 0, stream>>>(h, lnf_w, lnf_b, d_out);
}